// Round 8
// baseline (116.596 us; speedup 1.0000x reference)
//
#include <hip/hip_runtime.h>

// GAT, round 7: split k_sc into k_srt (per-batch sort/scan/coef, 64 blocks,
// no 4x redundancy) + k_tr (permuted-transposed hsT for vectorized sweeps)
// + k_emit (16B/lane vector loads instead of 512 scalar 2B gathers/thread).
// Algorithm: e_ij = leaky(s1_i + s2_j) rank-1 + monotone kink; sort j by s2,
// negative branch is a prefix per row:
//   out_i = c1_i*(U_N - U_{k_i}) + c2_i*V_{k_i};  O(N^2 F) -> O(N F).

typedef unsigned short u16;
typedef unsigned int   u32;
typedef unsigned long long u64;
typedef float  f32x4  __attribute__((ext_vector_type(4)));
typedef __bf16 bf16x8 __attribute__((ext_vector_type(8)));
typedef __bf16 bf16x4 __attribute__((ext_vector_type(4)));

#define NB    64
#define NENT  1024
#define FD    256
#define NROWS (NB * NENT)
#define ALPHA 0.2f

typedef __attribute__((address_space(1))) const void* gas_ptr;
typedef __attribute__((address_space(3))) void*       las_ptr;
__device__ __forceinline__ void gload16(const void* g, void* l) {
  __builtin_amdgcn_global_load_lds((gas_ptr)g, (las_ptr)l, 16, 0, 0);
}

// ---------------- k_wa: Wa1 = W@a1, Wa2 = W@a2 (fp32 exact) ----------------
__global__ __launch_bounds__(256) void k_wa(const float* __restrict__ W,
                                            const float* __restrict__ a,
                                            float* __restrict__ Wa1,
                                            float* __restrict__ Wa2) {
  const int k = blockIdx.x, f = threadIdx.x;
  const float w = W[(size_t)k * FD + f];
  float p1 = w * a[f];
  float p2 = w * a[FD + f];
#pragma unroll
  for (int off = 1; off < 64; off <<= 1) {
    p1 += __shfl_xor(p1, off, 64);
    p2 += __shfl_xor(p2, off, 64);
  }
  __shared__ float r1[4], r2[4];
  const int wv = f >> 6, lane = f & 63;
  if (lane == 0) { r1[wv] = p1; r2[wv] = p2; }
  __syncthreads();
  if (f == 0) {
    Wa1[k] = r1[0] + r1[1] + r1[2] + r1[3];
    Wa2[k] = r2[0] + r2[1] + r2[2] + r2[3];
  }
}

// ---------------- k_wt: Wt[f][k] = bf16(W[k][f]) ----------------
__global__ __launch_bounds__(256) void k_wt(const float* __restrict__ W,
                                            u16* __restrict__ Wt) {
  __shared__ float tile[64][65];
  const int t = threadIdx.x;
  const int ki = blockIdx.x >> 2, fi = blockIdx.x & 3;
  const int k0 = ki * 64, f0 = fi * 64;
  const int r = t >> 4, c4 = (t & 15) * 4;
#pragma unroll
  for (int it = 0; it < 4; ++it) {
    const int row = r + it * 16;
    float4 v = *(const float4*)&W[(size_t)(k0 + row) * FD + f0 + c4];
    tile[row][c4 + 0] = v.x; tile[row][c4 + 1] = v.y;
    tile[row][c4 + 2] = v.z; tile[row][c4 + 3] = v.w;
  }
  __syncthreads();
#pragma unroll
  for (int it = 0; it < 4; ++it) {
    const int fr = r + it * 16;
    bf16x4 pk;
    pk[0] = (__bf16)tile[c4 + 0][fr]; pk[1] = (__bf16)tile[c4 + 1][fr];
    pk[2] = (__bf16)tile[c4 + 2][fr]; pk[3] = (__bf16)tile[c4 + 3][fr];
    *(bf16x4*)&Wt[(size_t)(f0 + fr) * FD + k0 + c4] = pk;
  }
}

// -------- k_h: h = bf16(x@W) row-major, s1, s2 (256x256 tile, dbuf) --------
__global__ __launch_bounds__(512, 2) void k_h(
    const float* __restrict__ x, const u16* __restrict__ Wt,
    const float* __restrict__ Wa1g, const float* __restrict__ Wa2g,
    u16* __restrict__ h, float* __restrict__ s1, float* __restrict__ s2) {
  __shared__ __align__(16) char smem[67584];
  u16* Ab = (u16*)smem;                    // [2][4][256][8] = 32 KB
  u16* Bb = (u16*)(smem + 32768);          // [2][4][256][8] = 32 KB
  float* wa1 = (float*)(smem + 65536);
  float* wa2 = wa1 + FD;
  const int t = threadIdx.x;
  const int lane = t & 63, wv = t >> 6;
  const int wr = wv >> 2, wc = wv & 3;          // wave tile 128x64
  const int g16 = lane >> 4, c15 = lane & 15;
  const int p = blockIdx.x;
  const int lb = (p & 7) * 32 + (p >> 3);       // XCD-chunked
  const int rT = lb * 256;
  if (t < FD) { wa1[t] = Wa1g[t]; wa2[t] = Wa2g[t]; }
  const int row = t >> 1, half = t & 1;         // staging: 2 thr/row, 16 k
  const float* xsrc = x + (size_t)(rT + row) * FD + half * 16;
  float p1 = 0.f, p2 = 0.f;
  f32x4 acc[8][4];
  const f32x4 vz = {0.f, 0.f, 0.f, 0.f};
#pragma unroll
  for (int i = 0; i < 8; ++i)
#pragma unroll
    for (int j = 0; j < 4; ++j) acc[i][j] = vz;

  auto stage = [&](int nb, int kc, const float4& f0, const float4& f1,
                   const float4& f2, const float4& f3) {
    const int k0n = kc * 32;
    const int d0 = t;
    gload16(Wt + (size_t)(d0 & 255) * FD + k0n + (d0 >> 8) * 8,
            (char*)Bb + nb * 8192 * 2 + d0 * 16);
    const int d1 = t + 512;
    gload16(Wt + (size_t)(d1 & 255) * FD + k0n + (d1 >> 8) * 8,
            (char*)Bb + nb * 8192 * 2 + d1 * 16);
    bf16x8 w0, w1;
    w0[0] = (__bf16)f0.x; w0[1] = (__bf16)f0.y;
    w0[2] = (__bf16)f0.z; w0[3] = (__bf16)f0.w;
    w0[4] = (__bf16)f1.x; w0[5] = (__bf16)f1.y;
    w0[6] = (__bf16)f1.z; w0[7] = (__bf16)f1.w;
    w1[0] = (__bf16)f2.x; w1[1] = (__bf16)f2.y;
    w1[2] = (__bf16)f2.z; w1[3] = (__bf16)f2.w;
    w1[4] = (__bf16)f3.x; w1[5] = (__bf16)f3.y;
    w1[6] = (__bf16)f3.z; w1[7] = (__bf16)f3.w;
    *(bf16x8*)(Ab + ((nb * 4 + half * 2) * 256 + row) * 8) = w0;
    *(bf16x8*)(Ab + ((nb * 4 + half * 2 + 1) * 256 + row) * 8) = w1;
    const int kb = k0n + half * 16;
    p1 += f0.x*wa1[kb+ 0] + f0.y*wa1[kb+ 1] + f0.z*wa1[kb+ 2] + f0.w*wa1[kb+ 3]
        + f1.x*wa1[kb+ 4] + f1.y*wa1[kb+ 5] + f1.z*wa1[kb+ 6] + f1.w*wa1[kb+ 7]
        + f2.x*wa1[kb+ 8] + f2.y*wa1[kb+ 9] + f2.z*wa1[kb+10] + f2.w*wa1[kb+11]
        + f3.x*wa1[kb+12] + f3.y*wa1[kb+13] + f3.z*wa1[kb+14] + f3.w*wa1[kb+15];
    p2 += f0.x*wa2[kb+ 0] + f0.y*wa2[kb+ 1] + f0.z*wa2[kb+ 2] + f0.w*wa2[kb+ 3]
        + f1.x*wa2[kb+ 4] + f1.y*wa2[kb+ 5] + f1.z*wa2[kb+ 6] + f1.w*wa2[kb+ 7]
        + f2.x*wa2[kb+ 8] + f2.y*wa2[kb+ 9] + f2.z*wa2[kb+10] + f2.w*wa2[kb+11]
        + f3.x*wa2[kb+12] + f3.y*wa2[kb+13] + f3.z*wa2[kb+14] + f3.w*wa2[kb+15];
  };
  auto mfma_step = [&](int cb) {
    bf16x8 bfv[4];
#pragma unroll
    for (int fj = 0; fj < 4; ++fj)
      bfv[fj] = *(const bf16x8*)(Bb + ((cb * 4 + g16) * 256 + wc * 64 + fj * 16 + c15) * 8);
#pragma unroll
    for (int fi = 0; fi < 8; ++fi) {
      bf16x8 af = *(const bf16x8*)(Ab + ((cb * 4 + g16) * 256 + wr * 128 + fi * 16 + c15) * 8);
#pragma unroll
      for (int fj = 0; fj < 4; ++fj)
        acc[fi][fj] = __builtin_amdgcn_mfma_f32_16x16x32_bf16(
            af, bfv[fj], acc[fi][fj], 0, 0, 0);
    }
  };

  float4 xc0 = *(const float4*)(xsrc +  0);
  float4 xc1 = *(const float4*)(xsrc +  4);
  float4 xc2 = *(const float4*)(xsrc +  8);
  float4 xc3 = *(const float4*)(xsrc + 12);
  float4 xb0 = *(const float4*)(xsrc + 32);
  float4 xb1 = *(const float4*)(xsrc + 36);
  float4 xb2 = *(const float4*)(xsrc + 40);
  float4 xb3 = *(const float4*)(xsrc + 44);
  float4 xa0 = *(const float4*)(xsrc + 64);
  float4 xa1 = *(const float4*)(xsrc + 68);
  float4 xa2 = *(const float4*)(xsrc + 72);
  float4 xa3 = *(const float4*)(xsrc + 76);
  __syncthreads();                 // wa1/wa2 visible
  stage(0, 0, xc0, xc1, xc2, xc3);
  __syncthreads();                 // A[0] written, B[0] arrived
#pragma unroll 1
  for (int ks2 = 0; ks2 < 4; ++ks2) {
    stage(1, 2 * ks2 + 1, xb0, xb1, xb2, xb3);
    if (2 * ks2 + 3 < 8) {
      const float* s = xsrc + (2 * ks2 + 3) * 32;
      xb0 = *(const float4*)(s);      xb1 = *(const float4*)(s + 4);
      xb2 = *(const float4*)(s + 8);  xb3 = *(const float4*)(s + 12);
    }
    mfma_step(0);
    __syncthreads();
    if (2 * ks2 + 2 < 8) {
      stage(0, 2 * ks2 + 2, xa0, xa1, xa2, xa3);
      if (2 * ks2 + 4 < 8) {
        const float* s = xsrc + (2 * ks2 + 4) * 32;
        xa0 = *(const float4*)(s);      xa1 = *(const float4*)(s + 4);
        xa2 = *(const float4*)(s + 8);  xa3 = *(const float4*)(s + 12);
      }
    }
    mfma_step(1);
    __syncthreads();
  }
  // s1/s2: reduce 2 k-halves
  p1 += __shfl_xor(p1, 1, 64);
  p2 += __shfl_xor(p2, 1, 64);
  if (half == 0) { s1[rT + row] = p1; s2[rT + row] = p2; }
  // epilogue: row-major bf16 h via LDS repack (fully static acc indexing)
  u16* ep = (u16*)smem;   // 64 x 264 u16
#pragma unroll
  for (int hh = 0; hh < 4; ++hh) {
    if (wr == (hh >> 1)) {
#pragma unroll
      for (int fi2 = 0; fi2 < 4; ++fi2) {
        const int erow = fi2 * 16 + 4 * g16;
#pragma unroll
        for (int fj = 0; fj < 4; ++fj) {
          const int col = wc * 64 + fj * 16 + c15;
#pragma unroll
          for (int r = 0; r < 4; ++r) {
            __bf16 bv = (__bf16)acc[(hh & 1) * 4 + fi2][fj][r];
            ep[(erow + r) * 264 + col] = __builtin_bit_cast(u16, bv);
          }
        }
      }
    }
    __syncthreads();
    const int rrow = t >> 3, seg = t & 7;
    const u16* src = ep + rrow * 264 + seg * 32;
    u16* dst = h + (size_t)(rT + hh * 64 + rrow) * FD + seg * 32;
#pragma unroll
    for (int q = 0; q < 4; ++q)
      *(uint4*)(dst + q * 8) = *(const uint4*)(src + q * 8);
    __syncthreads();
  }
}

// -------- k_srt: per-batch sort(s2) + scans + coefs + buckets --------
__global__ __launch_bounds__(512) void k_srt(
    const float* __restrict__ s1, const float* __restrict__ s2,
    float* __restrict__ e2D, float* __restrict__ e2aD,
    float* __restrict__ c1D, float* __restrict__ c2D,
    u16* __restrict__ pidD, u16* __restrict__ iolD, u16* __restrict__ iblD) {
  __shared__ __align__(16) u64  kp[1024];
  __shared__ __align__(16) float key[1024];
  __shared__ __align__(16) u16   pid[1024];
  __shared__ __align__(16) float e2l[1024], e2al[1024];
  __shared__ __align__(16) float Su[1032], Sv[1032];
  __shared__ __align__(16) float c1l[1024], c2l[1024];
  __shared__ __align__(16) u32   cnt[1025];
  __shared__ __align__(16) u16   ibl[1032];
  __shared__ __align__(16) u16   iol[1024];
  __shared__ float UpS[8];
  const int t = threadIdx.x;
  const int b = blockIdx.x;
  const int w = t >> 6, lane = t & 63;

  // 1) packed sort keys
  auto packkey = [&](int j) {
    float v = s2[(size_t)b * NENT + j];
    u32 u = __builtin_bit_cast(u32, v);
    u32 su = u ^ (u32)(((int)u >> 31) | 0x80000000);
    kp[j] = ((u64)su << 32) | (u32)j;
  };
  packkey(t); packkey(t + 512);
  __syncthreads();
  // 2) bitonic sort ascending on u64
#pragma unroll 1
  for (int kk = 2; kk <= 1024; kk <<= 1) {
#pragma unroll 1
    for (int j = kk >> 1; j > 0; j >>= 1) {
      if (j >= 64) __syncthreads();
      else asm volatile("" ::: "memory");
      const int i  = ((t & ~(j - 1)) << 1) | (t & (j - 1));
      const int ix = i | j;
      const bool up = ((i & kk) == 0);
      u64 a = kp[i], c = kp[ix];
      const bool sw = up ? (a > c) : (a < c);
      if (sw) { kp[i] = c; kp[ix] = a; }
    }
  }
  __syncthreads();
  // 3) unpack + exp arrays
  auto unpack = [&](int r) {
    u64 v = kp[r];
    u32 su = (u32)(v >> 32);
    u32 ub = (su & 0x80000000u) ? (su ^ 0x80000000u) : ~su;
    float kv = __builtin_bit_cast(float, ub);
    key[r] = kv;
    pid[r] = (u16)(v & 0xFFFFu);
    e2l[r] = __expf(kv);
    e2al[r] = __expf(ALPHA * kv);
  };
  unpack(t); unpack(t + 512);
  __syncthreads();
  // 4) scans
  auto scanx = [&](const float* src, float* dst) {
    float a = src[2 * t], bb = src[2 * t + 1];
    float s = a + bb;
    float inc = s;
#pragma unroll
    for (int d = 1; d < 64; d <<= 1) {
      float o = __shfl_up(inc, d, 64);
      if (lane >= d) inc += o;
    }
    if (lane == 63) UpS[w] = inc;
    __syncthreads();
    float woff = 0.f;
#pragma unroll
    for (int w2 = 0; w2 < 8; ++w2) { float pv = UpS[w2]; if (w2 < w) woff += pv; }
    float P = woff + inc - s;
    dst[2 * t] = P; dst[2 * t + 1] = P + a;
    if (t == 511) dst[1024] = P + s;
    __syncthreads();
  };
  scanx(e2l, Su);
  scanx(e2al, Sv);
  // 5) per-i coefs + k_i
  const float s2max = key[1023];
  const float SuN = Su[1024];
  int kfA, kfB;
  cnt[t] = 0; cnt[t + 512] = 0;
  if (t == 0) cnt[1024] = 0;
  __syncthreads();
#pragma unroll
  for (int hi = 0; hi < 2; ++hi) {
    const int i = t + hi * 512;
    const float s1v = s1[(size_t)b * NENT + i];
    const float th = -s1v;
    int kf = 0;
#pragma unroll
    for (int d = 1024; d >= 1; d >>= 1)
      if (kf + d <= 1024 && key[kf + d - 1] < th) kf += d;
    const float qm = s1v + s2max;
    const float m = fmaxf(qm, ALPHA * qm);
    const float en1 = __expf(fminf(s1v - m, 80.f));
    const float en2 = __expf(fminf(ALPHA * s1v - m, 80.f));
    const float Z = en1 * (SuN - Su[kf]) + en2 * Sv[kf];
    const float rZ = 1.f / Z;
    c1l[i] = en1 * rZ; c2l[i] = en2 * rZ;
    if (hi == 0) kfA = kf; else kfB = kf;
    atomicAdd(&cnt[kf], 1u);
  }
  __syncthreads();
  // 6) exclusive scan of cnt -> ibl; zero cnt for cursors
  {
    float a = (float)cnt[2 * t], bb = (float)cnt[2 * t + 1];
    cnt[2 * t] = 0; cnt[2 * t + 1] = 0;
    if (t == 0) cnt[1024] = 0;
    float s = a + bb;
    float inc = s;
#pragma unroll
    for (int d = 1; d < 64; d <<= 1) {
      float o = __shfl_up(inc, d, 64);
      if (lane >= d) inc += o;
    }
    if (lane == 63) UpS[w] = inc;
    __syncthreads();
    float woff = 0.f;
#pragma unroll
    for (int w2 = 0; w2 < 8; ++w2) { float pv = UpS[w2]; if (w2 < w) woff += pv; }
    float P = woff + inc - s;
    ibl[2 * t] = (u16)P; ibl[2 * t + 1] = (u16)(P + a);
    if (t == 511) ibl[1024] = (u16)(P + s);
  }
  __syncthreads();
  // 7) scatter i's bucketed by k_i (CSR)
  {
    int pos = (int)ibl[kfA] + (int)atomicAdd(&cnt[kfA], 1u);
    pos = pos < 1023 ? pos : 1023;
    iol[pos] = (u16)t;
    int posB = (int)ibl[kfB] + (int)atomicAdd(&cnt[kfB], 1u);
    posB = posB < 1023 ? posB : 1023;
    iol[posB] = (u16)(t + 512);
  }
  __syncthreads();
  // 8) write descriptor to ws (coalesced)
  const size_t ob = (size_t)b * NENT;
  e2D [ob + t] = e2l[t];  e2D [ob + t + 512] = e2l[t + 512];
  e2aD[ob + t] = e2al[t]; e2aD[ob + t + 512] = e2al[t + 512];
  c1D [ob + t] = c1l[t];  c1D [ob + t + 512] = c1l[t + 512];
  c2D [ob + t] = c2l[t];  c2D [ob + t + 512] = c2l[t + 512];
  *(u32*)&pidD[ob + 2 * t] = *(const u32*)&pid[2 * t];
  *(u32*)&iolD[ob + 2 * t] = *(const u32*)&iol[2 * t];
  *(u32*)&iblD[(size_t)b * 1040 + 2 * t] = *(const u32*)&ibl[2 * t];
  if (t == 0) iblD[(size_t)b * 1040 + 1024] = ibl[1024];
}

// -------- k_tr: hsT[b][col][r] = h[b][pid[r]][col] (tiled transpose) --------
__global__ __launch_bounds__(512) void k_tr(
    const u16* __restrict__ h, const u16* __restrict__ pidD,
    u16* __restrict__ hsT) {
  __shared__ u16 pidl[1024];
  __shared__ u16 tile[2][64][72];
  const int t = threadIdx.x;
  const int cg = blockIdx.x, b = blockIdx.y;
  const int c0 = cg * 64;
  *(u32*)&pidl[2 * t] = *(const u32*)&pidD[(size_t)b * NENT + 2 * t];
  const int rs = t >> 3, seg = t & 7;    // read: 8 thr/row, 16B each
  const u16* hb = h + (size_t)b * NENT * FD;
  u16* hTb = hsT + (size_t)b * FD * NENT;
  __syncthreads();
  // stage iter 0
  {
    const int srow = pidl[rs];
    *(uint4*)&tile[0][rs][seg * 8] =
        *(const uint4*)&hb[(size_t)srow * FD + c0 + seg * 8];
  }
  __syncthreads();
#pragma unroll 1
  for (int it = 0; it < 16; ++it) {
    if (it < 15) {
      const int srow = pidl[(it + 1) * 64 + rs];
      *(uint4*)&tile[(it + 1) & 1][rs][seg * 8] =
          *(const uint4*)&hb[(size_t)srow * FD + c0 + seg * 8];
    }
    // write transposed: thread -> (col cs, 8-row seg)
    const int cs = t >> 3, rseg = t & 7;
    u16 tmp[8];
#pragma unroll
    for (int q = 0; q < 8; ++q) tmp[q] = tile[it & 1][rseg * 8 + q][cs];
    *(uint4*)&hTb[(size_t)(c0 + cs) * NENT + it * 64 + rseg * 8] =
        *(const uint4*)tmp;
    __syncthreads();
  }
}

// -------- k_emit: vectorized prefix sweeps + threshold emission --------
__global__ __launch_bounds__(512) void k_emit(
    const u16* __restrict__ hsT, const float* __restrict__ e2D,
    const float* __restrict__ e2aD, const float* __restrict__ c1D,
    const float* __restrict__ c2D, const u16* __restrict__ iolD,
    const u16* __restrict__ iblD, float* __restrict__ out) {
  __shared__ __align__(16) float e2l[1024], e2al[1024];
  __shared__ __align__(16) float c1l[1024], c2l[1024];
  __shared__ __align__(16) u16 ibl[1032], iol[1024];
  __shared__ float Up[8][64], Vp[8][64];
  const int t = threadIdx.x;
  const int cg = blockIdx.x, b = blockIdx.y;
  const int w = t >> 6, lane = t & 63;
  const size_t ob = (size_t)b * NENT;
  *(float2*)&e2l[2 * t]  = *(const float2*)&e2D[ob + 2 * t];
  *(float2*)&e2al[2 * t] = *(const float2*)&e2aD[ob + 2 * t];
  *(float2*)&c1l[2 * t]  = *(const float2*)&c1D[ob + 2 * t];
  *(float2*)&c2l[2 * t]  = *(const float2*)&c2D[ob + 2 * t];
  *(u32*)&iol[2 * t] = *(const u32*)&iolD[ob + 2 * t];
  *(u32*)&ibl[2 * t] = *(const u32*)&iblD[(size_t)b * 1040 + 2 * t];
  if (t == 0) ibl[1024] = iblD[(size_t)b * 1040 + 1024];
  __syncthreads();
  const int col = cg * 64 + lane;
  const u16* hcol = hsT + ((size_t)b * FD + col) * NENT;
  const int r0 = w * 128;
  // unpack helper: uint4 of 8 bf16 -> 8 f32 (exact bit placement)
  auto qf = [&](u32 uu, float* lo, float* hi) {
    *lo = __builtin_bit_cast(float, uu << 16);
    *hi = __builtin_bit_cast(float, uu & 0xFFFF0000u);
  };
  // sweep 1: wave partials
  float U = 0.f, V = 0.f;
#pragma unroll 1
  for (int g = 0; g < 16; ++g) {
    const int rb = r0 + g * 8;
    uint4 raw = *(const uint4*)(hcol + rb);
    float4 E0 = *(const float4*)&e2l[rb], E1 = *(const float4*)&e2l[rb + 4];
    float4 A0 = *(const float4*)&e2al[rb], A1 = *(const float4*)&e2al[rb + 4];
    float f0, f1, f2, f3, f4, f5, f6, f7;
    qf(raw.x, &f0, &f1); qf(raw.y, &f2, &f3);
    qf(raw.z, &f4, &f5); qf(raw.w, &f6, &f7);
    U += E0.x * f0 + E0.y * f1 + E0.z * f2 + E0.w * f3
       + E1.x * f4 + E1.y * f5 + E1.z * f6 + E1.w * f7;
    V += A0.x * f0 + A0.y * f1 + A0.z * f2 + A0.w * f3
       + A1.x * f4 + A1.y * f5 + A1.z * f6 + A1.w * f7;
  }
  Up[w][lane] = U; Vp[w][lane] = V;
  __syncthreads();
  float Uoff = 0.f, Voff = 0.f, UN = 0.f, VN = 0.f;
#pragma unroll
  for (int w2 = 0; w2 < 8; ++w2) {
    float a = Up[w2][lane], c = Vp[w2][lane];
    if (w2 < w) { Uoff += a; Voff += c; }
    UN += a; VN += c;
  }
  // sweep 2: running U,V + emissions at bucket boundaries
  U = Uoff; V = Voff;
#pragma unroll 1
  for (int g = 0; g < 16; ++g) {
    const int rb = r0 + g * 8;
    uint4 raw = *(const uint4*)(hcol + rb);
    float4 E0 = *(const float4*)&e2l[rb], E1 = *(const float4*)&e2l[rb + 4];
    float4 A0 = *(const float4*)&e2al[rb], A1 = *(const float4*)&e2al[rb + 4];
    uint4 ibraw = *(const uint4*)&ibl[rb];
    const u16* ib = (const u16*)&ibraw;
    const int ibn = ibl[rb + 8];
    float hf[8];
    qf(raw.x, &hf[0], &hf[1]); qf(raw.y, &hf[2], &hf[3]);
    qf(raw.z, &hf[4], &hf[5]); qf(raw.w, &hf[6], &hf[7]);
    const float* Ep = (const float*)&E0;   // E0,E1 contiguous? use arrays
    float Ev[8] = {E0.x, E0.y, E0.z, E0.w, E1.x, E1.y, E1.z, E1.w};
    float Av[8] = {A0.x, A0.y, A0.z, A0.w, A1.x, A1.y, A1.z, A1.w};
    (void)Ep;
#pragma unroll
    for (int u2 = 0; u2 < 8; ++u2) {
      const int e0 = ib[u2], e1 = (u2 < 7) ? (int)ib[u2 + 1] : ibn;
      for (int idx = e0; idx < e1; ++idx) {
        const int i = iol[idx];
        out[((size_t)b * NENT + i) * FD + col] = c1l[i] * (UN - U) + c2l[i] * V;
      }
      U += Ev[u2] * hf[u2]; V += Av[u2] * hf[u2];
    }
  }
  if (w == 7) {           // k_i == 1024 bucket (U==UN, V==VN here)
    const int e0 = ibl[1024];
    for (int idx = e0; idx < 1024; ++idx) {
      const int i = iol[idx];
      out[((size_t)b * NENT + i) * FD + col] = c1l[i] * (UN - U) + c2l[i] * V;
    }
  }
}

extern "C" void kernel_launch(void* const* d_in, const int* in_sizes, int n_in,
                              void* d_out, int out_size, void* d_ws, size_t ws_size,
                              hipStream_t stream) {
  const float* x = (const float*)d_in[0];
  const float* W = (const float*)d_in[1];
  const float* a = (const float*)d_in[2];
  float* out = (float*)d_out;

  char* ws = (char*)d_ws;
  u16*   h    = (u16*)ws;                          // 32 MB
  u16*   hsT  = (u16*)(ws + (size_t)33554432);     // 32 MB
  float* s1   = (float*)(ws + (size_t)67108864);   // 256 KB
  float* s2   = s1 + NROWS;                        // 256 KB
  float* Wa1  = s2 + NROWS;                        // 1 KB
  float* Wa2  = Wa1 + FD;                          // 1 KB
  u16*   Wt   = (u16*)(Wa2 + FD);                  // 128 KB
  float* e2D  = (float*)((char*)Wt + 131072);      // 256 KB
  float* e2aD = e2D + NROWS;                       // 256 KB
  float* c1D  = e2aD + NROWS;                      // 256 KB
  float* c2D  = c1D + NROWS;                       // 256 KB
  u16*   pidD = (u16*)(c2D + NROWS);               // 128 KB
  u16*   iolD = pidD + NROWS;                      // 128 KB
  u16*   iblD = iolD + NROWS;                      // ~133 KB  (total ~70 MB)

  k_wa<<<dim3(256), dim3(256), 0, stream>>>(W, a, Wa1, Wa2);
  k_wt<<<dim3(16), dim3(256), 0, stream>>>(W, Wt);
  k_h<<<dim3(256), dim3(512), 0, stream>>>(x, Wt, Wa1, Wa2, h, s1, s2);
  k_srt<<<dim3(NB), dim3(512), 0, stream>>>(s1, s2, e2D, e2aD, c1D, c2D,
                                            pidD, iolD, iblD);
  k_tr<<<dim3(4, NB), dim3(512), 0, stream>>>(h, pidD, hsT);
  k_emit<<<dim3(4, NB), dim3(512), 0, stream>>>(hsT, e2D, e2aD, c1D, c2D,
                                                iolD, iblD, out);
}

// Round 9
// 94.389 us; speedup vs baseline: 1.2353x; 1.2353x over previous
//
#include <hip/hip_runtime.h>

// GAT, round 8: emission phase restructured around a block-sum prefix table.
//   k_h   : h = bf16(x@W) row-major + s1,s2 (MFMA, unchanged)
//   k_srt : per-batch sort(s2) + scans + coefs + buckets (unchanged)
//   k_blk : Ublk/Vblk[b][q][col] = 64-row block sums of e2*h / e2a*h (sorted)
//   k_emit: 1024 blocks; each wave scans 64 rows starting from an exact
//           table offset; emits out_i = c1*(UN-U_{k_i}) + c2*V_{k_i}.
// No hsT transpose, no sweep-1: h gathered once, coalesced 128B/row/wave.

typedef unsigned short u16;
typedef unsigned int   u32;
typedef unsigned long long u64;
typedef float  f32x4  __attribute__((ext_vector_type(4)));
typedef __bf16 bf16x8 __attribute__((ext_vector_type(8)));
typedef __bf16 bf16x4 __attribute__((ext_vector_type(4)));

#define NB    64
#define NENT  1024
#define FD    256
#define NROWS (NB * NENT)
#define ALPHA 0.2f

typedef __attribute__((address_space(1))) const void* gas_ptr;
typedef __attribute__((address_space(3))) void*       las_ptr;
__device__ __forceinline__ void gload16(const void* g, void* l) {
  __builtin_amdgcn_global_load_lds((gas_ptr)g, (las_ptr)l, 16, 0, 0);
}

// ---------------- k_wa: Wa1 = W@a1, Wa2 = W@a2 (fp32 exact) ----------------
__global__ __launch_bounds__(256) void k_wa(const float* __restrict__ W,
                                            const float* __restrict__ a,
                                            float* __restrict__ Wa1,
                                            float* __restrict__ Wa2) {
  const int k = blockIdx.x, f = threadIdx.x;
  const float w = W[(size_t)k * FD + f];
  float p1 = w * a[f];
  float p2 = w * a[FD + f];
#pragma unroll
  for (int off = 1; off < 64; off <<= 1) {
    p1 += __shfl_xor(p1, off, 64);
    p2 += __shfl_xor(p2, off, 64);
  }
  __shared__ float r1[4], r2[4];
  const int wv = f >> 6, lane = f & 63;
  if (lane == 0) { r1[wv] = p1; r2[wv] = p2; }
  __syncthreads();
  if (f == 0) {
    Wa1[k] = r1[0] + r1[1] + r1[2] + r1[3];
    Wa2[k] = r2[0] + r2[1] + r2[2] + r2[3];
  }
}

// ---------------- k_wt: Wt[f][k] = bf16(W[k][f]) ----------------
__global__ __launch_bounds__(256) void k_wt(const float* __restrict__ W,
                                            u16* __restrict__ Wt) {
  __shared__ float tile[64][65];
  const int t = threadIdx.x;
  const int ki = blockIdx.x >> 2, fi = blockIdx.x & 3;
  const int k0 = ki * 64, f0 = fi * 64;
  const int r = t >> 4, c4 = (t & 15) * 4;
#pragma unroll
  for (int it = 0; it < 4; ++it) {
    const int row = r + it * 16;
    float4 v = *(const float4*)&W[(size_t)(k0 + row) * FD + f0 + c4];
    tile[row][c4 + 0] = v.x; tile[row][c4 + 1] = v.y;
    tile[row][c4 + 2] = v.z; tile[row][c4 + 3] = v.w;
  }
  __syncthreads();
#pragma unroll
  for (int it = 0; it < 4; ++it) {
    const int fr = r + it * 16;
    bf16x4 pk;
    pk[0] = (__bf16)tile[c4 + 0][fr]; pk[1] = (__bf16)tile[c4 + 1][fr];
    pk[2] = (__bf16)tile[c4 + 2][fr]; pk[3] = (__bf16)tile[c4 + 3][fr];
    *(bf16x4*)&Wt[(size_t)(f0 + fr) * FD + k0 + c4] = pk;
  }
}

// -------- k_h: h = bf16(x@W) row-major, s1, s2 (256x256 tile, dbuf) --------
__global__ __launch_bounds__(512, 2) void k_h(
    const float* __restrict__ x, const u16* __restrict__ Wt,
    const float* __restrict__ Wa1g, const float* __restrict__ Wa2g,
    u16* __restrict__ h, float* __restrict__ s1, float* __restrict__ s2) {
  __shared__ __align__(16) char smem[67584];
  u16* Ab = (u16*)smem;                    // [2][4][256][8] = 32 KB
  u16* Bb = (u16*)(smem + 32768);          // [2][4][256][8] = 32 KB
  float* wa1 = (float*)(smem + 65536);
  float* wa2 = wa1 + FD;
  const int t = threadIdx.x;
  const int lane = t & 63, wv = t >> 6;
  const int wr = wv >> 2, wc = wv & 3;          // wave tile 128x64
  const int g16 = lane >> 4, c15 = lane & 15;
  const int p = blockIdx.x;
  const int lb = (p & 7) * 32 + (p >> 3);       // XCD-chunked
  const int rT = lb * 256;
  if (t < FD) { wa1[t] = Wa1g[t]; wa2[t] = Wa2g[t]; }
  const int row = t >> 1, half = t & 1;         // staging: 2 thr/row, 16 k
  const float* xsrc = x + (size_t)(rT + row) * FD + half * 16;
  float p1 = 0.f, p2 = 0.f;
  f32x4 acc[8][4];
  const f32x4 vz = {0.f, 0.f, 0.f, 0.f};
#pragma unroll
  for (int i = 0; i < 8; ++i)
#pragma unroll
    for (int j = 0; j < 4; ++j) acc[i][j] = vz;

  auto stage = [&](int nb, int kc, const float4& f0, const float4& f1,
                   const float4& f2, const float4& f3) {
    const int k0n = kc * 32;
    const int d0 = t;
    gload16(Wt + (size_t)(d0 & 255) * FD + k0n + (d0 >> 8) * 8,
            (char*)Bb + nb * 8192 * 2 + d0 * 16);
    const int d1 = t + 512;
    gload16(Wt + (size_t)(d1 & 255) * FD + k0n + (d1 >> 8) * 8,
            (char*)Bb + nb * 8192 * 2 + d1 * 16);
    bf16x8 w0, w1;
    w0[0] = (__bf16)f0.x; w0[1] = (__bf16)f0.y;
    w0[2] = (__bf16)f0.z; w0[3] = (__bf16)f0.w;
    w0[4] = (__bf16)f1.x; w0[5] = (__bf16)f1.y;
    w0[6] = (__bf16)f1.z; w0[7] = (__bf16)f1.w;
    w1[0] = (__bf16)f2.x; w1[1] = (__bf16)f2.y;
    w1[2] = (__bf16)f2.z; w1[3] = (__bf16)f2.w;
    w1[4] = (__bf16)f3.x; w1[5] = (__bf16)f3.y;
    w1[6] = (__bf16)f3.z; w1[7] = (__bf16)f3.w;
    *(bf16x8*)(Ab + ((nb * 4 + half * 2) * 256 + row) * 8) = w0;
    *(bf16x8*)(Ab + ((nb * 4 + half * 2 + 1) * 256 + row) * 8) = w1;
    const int kb = k0n + half * 16;
    p1 += f0.x*wa1[kb+ 0] + f0.y*wa1[kb+ 1] + f0.z*wa1[kb+ 2] + f0.w*wa1[kb+ 3]
        + f1.x*wa1[kb+ 4] + f1.y*wa1[kb+ 5] + f1.z*wa1[kb+ 6] + f1.w*wa1[kb+ 7]
        + f2.x*wa1[kb+ 8] + f2.y*wa1[kb+ 9] + f2.z*wa1[kb+10] + f2.w*wa1[kb+11]
        + f3.x*wa1[kb+12] + f3.y*wa1[kb+13] + f3.z*wa1[kb+14] + f3.w*wa1[kb+15];
    p2 += f0.x*wa2[kb+ 0] + f0.y*wa2[kb+ 1] + f0.z*wa2[kb+ 2] + f0.w*wa2[kb+ 3]
        + f1.x*wa2[kb+ 4] + f1.y*wa2[kb+ 5] + f1.z*wa2[kb+ 6] + f1.w*wa2[kb+ 7]
        + f2.x*wa2[kb+ 8] + f2.y*wa2[kb+ 9] + f2.z*wa2[kb+10] + f2.w*wa2[kb+11]
        + f3.x*wa2[kb+12] + f3.y*wa2[kb+13] + f3.z*wa2[kb+14] + f3.w*wa2[kb+15];
  };
  auto mfma_step = [&](int cb) {
    bf16x8 bfv[4];
#pragma unroll
    for (int fj = 0; fj < 4; ++fj)
      bfv[fj] = *(const bf16x8*)(Bb + ((cb * 4 + g16) * 256 + wc * 64 + fj * 16 + c15) * 8);
#pragma unroll
    for (int fi = 0; fi < 8; ++fi) {
      bf16x8 af = *(const bf16x8*)(Ab + ((cb * 4 + g16) * 256 + wr * 128 + fi * 16 + c15) * 8);
#pragma unroll
      for (int fj = 0; fj < 4; ++fj)
        acc[fi][fj] = __builtin_amdgcn_mfma_f32_16x16x32_bf16(
            af, bfv[fj], acc[fi][fj], 0, 0, 0);
    }
  };

  float4 xc0 = *(const float4*)(xsrc +  0);
  float4 xc1 = *(const float4*)(xsrc +  4);
  float4 xc2 = *(const float4*)(xsrc +  8);
  float4 xc3 = *(const float4*)(xsrc + 12);
  float4 xb0 = *(const float4*)(xsrc + 32);
  float4 xb1 = *(const float4*)(xsrc + 36);
  float4 xb2 = *(const float4*)(xsrc + 40);
  float4 xb3 = *(const float4*)(xsrc + 44);
  float4 xa0 = *(const float4*)(xsrc + 64);
  float4 xa1 = *(const float4*)(xsrc + 68);
  float4 xa2 = *(const float4*)(xsrc + 72);
  float4 xa3 = *(const float4*)(xsrc + 76);
  __syncthreads();                 // wa1/wa2 visible
  stage(0, 0, xc0, xc1, xc2, xc3);
  __syncthreads();                 // A[0] written, B[0] arrived
#pragma unroll 1
  for (int ks2 = 0; ks2 < 4; ++ks2) {
    stage(1, 2 * ks2 + 1, xb0, xb1, xb2, xb3);
    if (2 * ks2 + 3 < 8) {
      const float* s = xsrc + (2 * ks2 + 3) * 32;
      xb0 = *(const float4*)(s);      xb1 = *(const float4*)(s + 4);
      xb2 = *(const float4*)(s + 8);  xb3 = *(const float4*)(s + 12);
    }
    mfma_step(0);
    __syncthreads();
    if (2 * ks2 + 2 < 8) {
      stage(0, 2 * ks2 + 2, xa0, xa1, xa2, xa3);
      if (2 * ks2 + 4 < 8) {
        const float* s = xsrc + (2 * ks2 + 4) * 32;
        xa0 = *(const float4*)(s);      xa1 = *(const float4*)(s + 4);
        xa2 = *(const float4*)(s + 8);  xa3 = *(const float4*)(s + 12);
      }
    }
    mfma_step(1);
    __syncthreads();
  }
  // s1/s2: reduce 2 k-halves
  p1 += __shfl_xor(p1, 1, 64);
  p2 += __shfl_xor(p2, 1, 64);
  if (half == 0) { s1[rT + row] = p1; s2[rT + row] = p2; }
  // epilogue: row-major bf16 h via LDS repack (fully static acc indexing)
  u16* ep = (u16*)smem;   // 64 x 264 u16
#pragma unroll
  for (int hh = 0; hh < 4; ++hh) {
    if (wr == (hh >> 1)) {
#pragma unroll
      for (int fi2 = 0; fi2 < 4; ++fi2) {
        const int erow = fi2 * 16 + 4 * g16;
#pragma unroll
        for (int fj = 0; fj < 4; ++fj) {
          const int col = wc * 64 + fj * 16 + c15;
#pragma unroll
          for (int r = 0; r < 4; ++r) {
            __bf16 bv = (__bf16)acc[(hh & 1) * 4 + fi2][fj][r];
            ep[(erow + r) * 264 + col] = __builtin_bit_cast(u16, bv);
          }
        }
      }
    }
    __syncthreads();
    const int rrow = t >> 3, seg = t & 7;
    const u16* src = ep + rrow * 264 + seg * 32;
    u16* dst = h + (size_t)(rT + hh * 64 + rrow) * FD + seg * 32;
#pragma unroll
    for (int q = 0; q < 4; ++q)
      *(uint4*)(dst + q * 8) = *(const uint4*)(src + q * 8);
    __syncthreads();
  }
}

// -------- k_srt: per-batch sort(s2) + scans + coefs + buckets --------
__global__ __launch_bounds__(512) void k_srt(
    const float* __restrict__ s1, const float* __restrict__ s2,
    float* __restrict__ e2D, float* __restrict__ e2aD,
    float* __restrict__ c1D, float* __restrict__ c2D,
    u16* __restrict__ pidD, u16* __restrict__ iolD, u16* __restrict__ iblD) {
  __shared__ __align__(16) u64  kp[1024];
  __shared__ __align__(16) float key[1024];
  __shared__ __align__(16) u16   pid[1024];
  __shared__ __align__(16) float e2l[1024], e2al[1024];
  __shared__ __align__(16) float Su[1032], Sv[1032];
  __shared__ __align__(16) float c1l[1024], c2l[1024];
  __shared__ __align__(16) u32   cnt[1025];
  __shared__ __align__(16) u16   ibl[1032];
  __shared__ __align__(16) u16   iol[1024];
  __shared__ float UpS[8];
  const int t = threadIdx.x;
  const int b = blockIdx.x;
  const int w = t >> 6, lane = t & 63;

  auto packkey = [&](int j) {
    float v = s2[(size_t)b * NENT + j];
    u32 u = __builtin_bit_cast(u32, v);
    u32 su = u ^ (u32)(((int)u >> 31) | 0x80000000);
    kp[j] = ((u64)su << 32) | (u32)j;
  };
  packkey(t); packkey(t + 512);
  __syncthreads();
#pragma unroll 1
  for (int kk = 2; kk <= 1024; kk <<= 1) {
#pragma unroll 1
    for (int j = kk >> 1; j > 0; j >>= 1) {
      if (j >= 64) __syncthreads();
      else asm volatile("" ::: "memory");
      const int i  = ((t & ~(j - 1)) << 1) | (t & (j - 1));
      const int ix = i | j;
      const bool up = ((i & kk) == 0);
      u64 a = kp[i], c = kp[ix];
      const bool sw = up ? (a > c) : (a < c);
      if (sw) { kp[i] = c; kp[ix] = a; }
    }
  }
  __syncthreads();
  auto unpack = [&](int r) {
    u64 v = kp[r];
    u32 su = (u32)(v >> 32);
    u32 ub = (su & 0x80000000u) ? (su ^ 0x80000000u) : ~su;
    float kv = __builtin_bit_cast(float, ub);
    key[r] = kv;
    pid[r] = (u16)(v & 0xFFFFu);
    e2l[r] = __expf(kv);
    e2al[r] = __expf(ALPHA * kv);
  };
  unpack(t); unpack(t + 512);
  __syncthreads();
  auto scanx = [&](const float* src, float* dst) {
    float a = src[2 * t], bb = src[2 * t + 1];
    float s = a + bb;
    float inc = s;
#pragma unroll
    for (int d = 1; d < 64; d <<= 1) {
      float o = __shfl_up(inc, d, 64);
      if (lane >= d) inc += o;
    }
    if (lane == 63) UpS[w] = inc;
    __syncthreads();
    float woff = 0.f;
#pragma unroll
    for (int w2 = 0; w2 < 8; ++w2) { float pv = UpS[w2]; if (w2 < w) woff += pv; }
    float P = woff + inc - s;
    dst[2 * t] = P; dst[2 * t + 1] = P + a;
    if (t == 511) dst[1024] = P + s;
    __syncthreads();
  };
  scanx(e2l, Su);
  scanx(e2al, Sv);
  const float s2max = key[1023];
  const float SuN = Su[1024];
  int kfA, kfB;
  cnt[t] = 0; cnt[t + 512] = 0;
  if (t == 0) cnt[1024] = 0;
  __syncthreads();
#pragma unroll
  for (int hi = 0; hi < 2; ++hi) {
    const int i = t + hi * 512;
    const float s1v = s1[(size_t)b * NENT + i];
    const float th = -s1v;
    int kf = 0;
#pragma unroll
    for (int d = 1024; d >= 1; d >>= 1)
      if (kf + d <= 1024 && key[kf + d - 1] < th) kf += d;
    const float qm = s1v + s2max;
    const float m = fmaxf(qm, ALPHA * qm);
    const float en1 = __expf(fminf(s1v - m, 80.f));
    const float en2 = __expf(fminf(ALPHA * s1v - m, 80.f));
    const float Z = en1 * (SuN - Su[kf]) + en2 * Sv[kf];
    const float rZ = 1.f / Z;
    c1l[i] = en1 * rZ; c2l[i] = en2 * rZ;
    if (hi == 0) kfA = kf; else kfB = kf;
    atomicAdd(&cnt[kf], 1u);
  }
  __syncthreads();
  {
    float a = (float)cnt[2 * t], bb = (float)cnt[2 * t + 1];
    cnt[2 * t] = 0; cnt[2 * t + 1] = 0;
    if (t == 0) cnt[1024] = 0;
    float s = a + bb;
    float inc = s;
#pragma unroll
    for (int d = 1; d < 64; d <<= 1) {
      float o = __shfl_up(inc, d, 64);
      if (lane >= d) inc += o;
    }
    if (lane == 63) UpS[w] = inc;
    __syncthreads();
    float woff = 0.f;
#pragma unroll
    for (int w2 = 0; w2 < 8; ++w2) { float pv = UpS[w2]; if (w2 < w) woff += pv; }
    float P = woff + inc - s;
    ibl[2 * t] = (u16)P; ibl[2 * t + 1] = (u16)(P + a);
    if (t == 511) ibl[1024] = (u16)(P + s);
  }
  __syncthreads();
  {
    int pos = (int)ibl[kfA] + (int)atomicAdd(&cnt[kfA], 1u);
    pos = pos < 1023 ? pos : 1023;
    iol[pos] = (u16)t;
    int posB = (int)ibl[kfB] + (int)atomicAdd(&cnt[kfB], 1u);
    posB = posB < 1023 ? posB : 1023;
    iol[posB] = (u16)(t + 512);
  }
  __syncthreads();
  const size_t ob = (size_t)b * NENT;
  e2D [ob + t] = e2l[t];  e2D [ob + t + 512] = e2l[t + 512];
  e2aD[ob + t] = e2al[t]; e2aD[ob + t + 512] = e2al[t + 512];
  c1D [ob + t] = c1l[t];  c1D [ob + t + 512] = c1l[t + 512];
  c2D [ob + t] = c2l[t];  c2D [ob + t + 512] = c2l[t + 512];
  *(u32*)&pidD[ob + 2 * t] = *(const u32*)&pid[2 * t];
  *(u32*)&iolD[ob + 2 * t] = *(const u32*)&iol[2 * t];
  *(u32*)&iblD[(size_t)b * 1040 + 2 * t] = *(const u32*)&ibl[2 * t];
  if (t == 0) iblD[(size_t)b * 1040 + 1024] = ibl[1024];
}

// -------- k_blk: 64-row block sums of e2*h, e2a*h over sorted order --------
__global__ __launch_bounds__(256) void k_blk(
    const u16* __restrict__ h, const u16* __restrict__ pidD,
    const float* __restrict__ e2D, const float* __restrict__ e2aD,
    float* __restrict__ Ublk, float* __restrict__ Vblk) {
  __shared__ u16 pids[64];
  __shared__ float e2s[64], e2as[64];
  const int t = threadIdx.x;            // col
  const int q = blockIdx.x, b = blockIdx.y;
  const int rb = q * 64;
  if (t < 64) pids[t] = pidD[(size_t)b * NENT + rb + t];
  else if (t < 128) e2s[t - 64] = e2D[(size_t)b * NENT + rb + t - 64];
  else if (t < 192) e2as[t - 128] = e2aD[(size_t)b * NENT + rb + t - 128];
  __syncthreads();
  const u16* hb = h + (size_t)b * NENT * FD + t;
  float U = 0.f, V = 0.f;
  float ha[8], hc[8];
  auto ld8 = [&](float* dv, int r) {
#pragma unroll
    for (int u = 0; u < 8; ++u) {
      u32 raw = hb[(size_t)pids[r + u] * FD];
      dv[u] = __builtin_bit_cast(float, raw << 16);
    }
  };
  ld8(ha, 0);
#pragma unroll 1
  for (int g = 0; g < 4; ++g) {
    ld8(hc, g * 16 + 8);
#pragma unroll
    for (int u = 0; u < 8; ++u) {
      U += e2s[g * 16 + u] * ha[u]; V += e2as[g * 16 + u] * ha[u];
    }
    if (g < 3) ld8(ha, g * 16 + 16);
#pragma unroll
    for (int u = 0; u < 8; ++u) {
      U += e2s[g * 16 + 8 + u] * hc[u]; V += e2as[g * 16 + 8 + u] * hc[u];
    }
  }
  Ublk[((size_t)b * 16 + q) * FD + t] = U;
  Vblk[((size_t)b * 16 + q) * FD + t] = V;
}

// -------- k_emit: table-offset scan (64 rows/wave) + threshold emission ----
__global__ __launch_bounds__(256) void k_emit(
    const u16* __restrict__ h, const u16* __restrict__ pidD,
    const float* __restrict__ e2D, const float* __restrict__ e2aD,
    const float* __restrict__ c1D, const float* __restrict__ c2D,
    const u16* __restrict__ iolD, const u16* __restrict__ iblD,
    const float* __restrict__ Ublk, const float* __restrict__ Vblk,
    float* __restrict__ out) {
  __shared__ __align__(16) float c1l[1024], c2l[1024];
  __shared__ __align__(16) u16 iol[1024];
  __shared__ __align__(16) float e2s[256], e2as[256];
  __shared__ __align__(16) u16 pids[256];
  __shared__ __align__(16) u16 iblS[260];
  const int t = threadIdx.x;
  const int bx = blockIdx.x, b = blockIdx.y;
  const int cg = bx & 3, rq = bx >> 2;
  const int w = t >> 6, lane = t & 63;
  const size_t ob = (size_t)b * NENT;
  // cooperative LDS loads
  *(float4*)&c1l[4 * t] = *(const float4*)&c1D[ob + 4 * t];
  *(float4*)&c2l[4 * t] = *(const float4*)&c2D[ob + 4 * t];
  *(uint2*)&iol[4 * t] = *(const uint2*)&iolD[ob + 4 * t];
  e2s[t]  = e2D[ob + rq * 256 + t];
  e2as[t] = e2aD[ob + rq * 256 + t];
  pids[t] = pidD[ob + rq * 256 + t];
  iblS[t] = iblD[(size_t)b * 1040 + rq * 256 + t];
  if (t == 0) iblS[256] = iblD[(size_t)b * 1040 + rq * 256 + 256];
  __syncthreads();
  const int col = cg * 64 + lane;
  // exact scan offset from the block-sum table
  const int qstart = rq * 4 + w;
  float Uoff = 0.f, Voff = 0.f, UN = 0.f, VN = 0.f;
#pragma unroll
  for (int q = 0; q < 16; ++q) {
    float uu = Ublk[((size_t)b * 16 + q) * FD + col];
    float vv = Vblk[((size_t)b * 16 + q) * FD + col];
    if (q < qstart) { Uoff += uu; Voff += vv; }
    UN += uu; VN += vv;
  }
  const u16* hb = h + ob * FD + col;
  float U = Uoff, V = Voff;
  float ha[8], hc[8];
  auto ld8 = [&](float* dv, int lr) {
#pragma unroll
    for (int u = 0; u < 8; ++u) {
      u32 raw = hb[(size_t)pids[lr + u] * FD];
      dv[u] = __builtin_bit_cast(float, raw << 16);
    }
  };
  const int lr0 = w * 64;
  ld8(ha, lr0);
#pragma unroll 1
  for (int g = 0; g < 4; ++g) {
    const int lb0 = lr0 + g * 16;
    ld8(hc, lb0 + 8);
#pragma unroll
    for (int u = 0; u < 8; ++u) {
      const int lr = lb0 + u;
      const int e0 = iblS[lr], e1 = iblS[lr + 1];
      for (int idx = e0; idx < e1; ++idx) {
        const int i = iol[idx];
        out[(ob + i) * FD + col] = c1l[i] * (UN - U) + c2l[i] * V;
      }
      U += e2s[lr] * ha[u]; V += e2as[lr] * ha[u];
    }
    if (g < 3) ld8(ha, lb0 + 16);
#pragma unroll
    for (int u = 0; u < 8; ++u) {
      const int lr = lb0 + 8 + u;
      const int e0 = iblS[lr], e1 = iblS[lr + 1];
      for (int idx = e0; idx < e1; ++idx) {
        const int i = iol[idx];
        out[(ob + i) * FD + col] = c1l[i] * (UN - U) + c2l[i] * V;
      }
      U += e2s[lr] * hc[u]; V += e2as[lr] * hc[u];
    }
  }
  if (rq == 3 && w == 3) {   // final bucket k_i == 1024 (U==UN, V==VN here)
    const int e0 = iblS[256];
    for (int idx = e0; idx < NENT; ++idx) {
      const int i = iol[idx];
      out[(ob + i) * FD + col] = c1l[i] * (UN - U) + c2l[i] * V;
    }
  }
}

extern "C" void kernel_launch(void* const* d_in, const int* in_sizes, int n_in,
                              void* d_out, int out_size, void* d_ws, size_t ws_size,
                              hipStream_t stream) {
  const float* x = (const float*)d_in[0];
  const float* W = (const float*)d_in[1];
  const float* a = (const float*)d_in[2];
  float* out = (float*)d_out;

  char* ws = (char*)d_ws;
  u16*   h    = (u16*)ws;                          // 32 MB
  float* s1   = (float*)(ws + (size_t)33554432);   // 256 KB
  float* s2   = s1 + NROWS;                        // 256 KB
  float* Wa1  = s2 + NROWS;                        // 1 KB
  float* Wa2  = Wa1 + FD;                          // 1 KB
  u16*   Wt   = (u16*)(Wa2 + FD);                  // 128 KB
  float* e2D  = (float*)((char*)Wt + 131072);      // 256 KB
  float* e2aD = e2D + NROWS;                       // 256 KB
  float* c1D  = e2aD + NROWS;                      // 256 KB
  float* c2D  = c1D + NROWS;                       // 256 KB
  u16*   pidD = (u16*)(c2D + NROWS);               // 128 KB
  u16*   iolD = pidD + NROWS;                      // 128 KB
  u16*   iblD = iolD + NROWS;                      // ~133 KB
  float* Ublk = (float*)((char*)iblD + 1040 * NB * 2); // 1 MB
  float* Vblk = Ublk + NB * 16 * FD;                   // 1 MB (~38 MB total)

  k_wa<<<dim3(256), dim3(256), 0, stream>>>(W, a, Wa1, Wa2);
  k_wt<<<dim3(16), dim3(256), 0, stream>>>(W, Wt);
  k_h<<<dim3(256), dim3(512), 0, stream>>>(x, Wt, Wa1, Wa2, h, s1, s2);
  k_srt<<<dim3(NB), dim3(512), 0, stream>>>(s1, s2, e2D, e2aD, c1D, c2D,
                                            pidD, iolD, iblD);
  k_blk<<<dim3(16, NB), dim3(256), 0, stream>>>(h, pidD, e2D, e2aD, Ublk, Vblk);
  k_emit<<<dim3(16, NB), dim3(256), 0, stream>>>(h, pidD, e2D, e2aD, c1D, c2D,
                                                 iolD, iblD, Ublk, Vblk, out);
}